// Round 4
// baseline (1296.777 us; speedup 1.0000x reference)
//
#include <hip/hip_runtime.h>
#include <math.h>

// Elman RNN via MFMA (bf16 hi/lo split), fused persistent kernel.
// x:(S,B,I) f32; W1:(H,I); b1:(H); W2:(H,H); b2:(H)
// out: h_seq (S,B,H) f32 then h_last (1,B,H) f32.
//
// Grid = 32 blocks, one batch tile of 16 rows each (recurrences independent).
// Block = 512 thr = 8 waves; wave w owns output units [16w,16w+16).
// Per step: D(16x16 per wave) = h(16x128)*W2^T + x(16x64)*W1^T + bias, tanh,
// computed as mfma_f32_16x16x32_bf16 with every operand split hi+lo bf16:
//   W_hi*v_hi + W_hi*v_lo + W_lo*v_hi   (lo*lo dropped, ~2^-18)
// -> effective ~f32 precision. Weight fragments are loop-invariant registers
// (AGPR-parking is fine: mfma reads AGPRs; rounds 2-3 showed the VALU path
// loses to regalloc AGPR spills).
// h goes through XOR-swizzled LDS bf16 planes each step (one s_barrier/step,
// lgkmcnt only -- never drain the h_seq global stores). x prefetched 2 steps
// ahead via ping-pong float2 regs.

#define S_LEN 2048
#define B_SZ  512
#define I_SZ  64
#define H_SZ  128
#define BT    16
#define BLK   512
#define HROW  256   // bytes per h-plane row (128 bf16)
#define XROW  128   // bytes per x-plane row (64 bf16)

typedef short bf16x8 __attribute__((ext_vector_type(8)));
typedef float f32x4  __attribute__((ext_vector_type(4)));

#define MFMA(A, B, C) __builtin_amdgcn_mfma_f32_16x16x32_bf16((A), (B), (C), 0, 0, 0)

#define LDS_BARRIER()                                        \
    asm volatile("s_waitcnt lgkmcnt(0)" ::: "memory");       \
    __builtin_amdgcn_s_barrier();                            \
    asm volatile("" ::: "memory")

__device__ __forceinline__ unsigned short bf_trunc(float v) {
    union { float f; unsigned u; } x; x.f = v;
    return (unsigned short)(x.u >> 16);
}
__device__ __forceinline__ float bf_to_f(unsigned short h) {
    union { float f; unsigned u; } x; x.u = ((unsigned)h) << 16;
    return x.f;
}

__global__ __launch_bounds__(BLK) void rnn_mfma(
    const float* __restrict__ x,
    const float* __restrict__ W1,
    const float* __restrict__ b1,
    const float* __restrict__ W2,
    const float* __restrict__ b2,
    float* __restrict__ out)
{
    const int tid  = threadIdx.x;
    const int lane = tid & 63;
    const int w    = tid >> 6;          // wave 0..7 -> N-tile
    const int l15  = lane & 15;
    const int l4   = lane >> 4;         // k-group 0..3
    const int unit = (w << 4) + l15;    // output unit (B-frag col / C col)
    const int b0   = blockIdx.x * BT;

    __shared__ short hpl_hi[2][BT * H_SZ];
    __shared__ short hpl_lo[2][BT * H_SZ];
    __shared__ short xpl_hi[2][BT * I_SZ];
    __shared__ short xpl_lo[2][BT * I_SZ];

    // ---- loop-invariant weight B-fragments (hi/lo split) ----
    // B slot (lane,j) <- Wt[k][n] = W[n][k], n=unit, k = 32c + l4*8 + j.
    bf16x8 w2h[4], w2l[4], w1h[2], w1l[2];
    #pragma unroll
    for (int c = 0; c < 4; ++c) {
        #pragma unroll
        for (int j = 0; j < 8; ++j) {
            float v = W2[unit * H_SZ + 32 * c + l4 * 8 + j];
            unsigned short hi = bf_trunc(v);
            unsigned short lo = bf_trunc(v - bf_to_f(hi));
            w2h[c][j] = (short)hi; w2l[c][j] = (short)lo;
        }
    }
    #pragma unroll
    for (int c = 0; c < 2; ++c) {
        #pragma unroll
        for (int j = 0; j < 8; ++j) {
            float v = W1[unit * I_SZ + 32 * c + l4 * 8 + j];
            unsigned short hi = bf_trunc(v);
            unsigned short lo = bf_trunc(v - bf_to_f(hi));
            w1h[c][j] = (short)hi; w1l[c][j] = (short)lo;
        }
    }
    const float zb = b1[unit] + b2[unit];

    // ---- per-thread LDS byte offsets (XOR-swizzled) ----
    int hro[4], xro[2], woh[4];
    #pragma unroll
    for (int c = 0; c < 4; ++c)
        hro[c] = l15 * HROW + ((64 * c + l4 * 16) ^ ((l15 & 7) << 4));
    #pragma unroll
    for (int c = 0; c < 2; ++c)
        xro[c] = l15 * XROW + ((64 * c + l4 * 16) ^ ((l15 & 7) << 4));
    #pragma unroll
    for (int r = 0; r < 4; ++r) {
        int row = (l4 << 2) + r;
        woh[r] = row * HROW + ((unit * 2) ^ ((row & 7) << 4));
    }
    const int xr  = tid >> 5;            // x stage: row 0..15
    const int xc  = (tid & 31) * 2;      // col pair base
    const int wox = xr * XROW + ((xc * 2) ^ ((xr & 7) << 4));

    // ---- prologue: stage x0 -> xpl[0]; issue load of x1 ----
    {
        float2 v0 = *(const float2*)(x + ((size_t)0 * B_SZ + b0 + xr) * I_SZ + xc);
        unsigned short h0 = bf_trunc(v0.x), h1 = bf_trunc(v0.y);
        unsigned short g0 = bf_trunc(v0.x - bf_to_f(h0));
        unsigned short g1 = bf_trunc(v0.y - bf_to_f(h1));
        *(unsigned*)((char*)xpl_hi[0] + wox) = (unsigned)h0 | ((unsigned)h1 << 16);
        *(unsigned*)((char*)xpl_lo[0] + wox) = (unsigned)g0 | ((unsigned)g1 << 16);
    }
    float2 xgA = *(const float2*)(x + ((size_t)1 * B_SZ + b0 + xr) * I_SZ + xc);
    float2 xgB;

    LDS_BARRIER();

    // ---- A-fragments for step 0: h = 0, x from xpl[0] ----
    bf16x8 ah[4], al[4], xh[2], xl[2];
    #pragma unroll
    for (int c = 0; c < 4; ++c) { ah[c] = (bf16x8){0,0,0,0,0,0,0,0}; al[c] = ah[c]; }
    #pragma unroll
    for (int c = 0; c < 2; ++c) {
        xh[c] = *(const bf16x8*)((const char*)xpl_hi[0] + xro[c]);
        xl[c] = *(const bf16x8*)((const char*)xpl_lo[0] + xro[c]);
    }

#define STEP(S, XGC, XGL, HB)                                                 \
{                                                                             \
    /* issue x global load for step S+2 (used two steps later) */             \
    { int sp = (S) + 2; if (sp > S_LEN - 1) sp = S_LEN - 1;                   \
      XGL = *(const float2*)(x + ((size_t)sp * B_SZ + b0 + xr) * I_SZ + xc); }\
    f32x4 accA = {zb, zb, zb, zb};                                            \
    f32x4 accB = {0.f, 0.f, 0.f, 0.f};                                       \
    f32x4 accC = {0.f, 0.f, 0.f, 0.f};                                       \
    accA = MFMA(ah[0], w2h[0], accA);  accB = MFMA(al[0], w2h[0], accB);      \
    accC = MFMA(ah[0], w2l[0], accC);                                         \
    accA = MFMA(ah[1], w2h[1], accA);  accB = MFMA(al[1], w2h[1], accB);      \
    accC = MFMA(ah[1], w2l[1], accC);                                         \
    accA = MFMA(ah[2], w2h[2], accA);  accB = MFMA(al[2], w2h[2], accB);      \
    accC = MFMA(ah[2], w2l[2], accC);                                         \
    accA = MFMA(ah[3], w2h[3], accA);  accB = MFMA(al[3], w2h[3], accB);      \
    accC = MFMA(ah[3], w2l[3], accC);                                         \
    accA = MFMA(xh[0], w1h[0], accA);  accB = MFMA(xl[0], w1h[0], accB);      \
    accC = MFMA(xh[0], w1l[0], accC);                                         \
    accA = MFMA(xh[1], w1h[1], accA);  accB = MFMA(xl[1], w1h[1], accB);      \
    accC = MFMA(xh[1], w1l[1], accC);                                         \
    f32x4 acc = (accA + accB) + accC;                                         \
    /* epilogue: tanh, h_seq store, split -> LDS h planes */                  \
    _Pragma("unroll")                                                         \
    for (int r = 0; r < 4; ++r) {                                             \
        float a = acc[r];                                                     \
        float t = 1.0f - 2.0f * __builtin_amdgcn_rcpf(1.0f + __expf(2.0f*a)); \
        int row = (l4 << 2) + r;                                              \
        out[((size_t)(S) * B_SZ + b0 + row) * H_SZ + unit] = t;               \
        unsigned short hi = bf_trunc(t);                                      \
        unsigned short lo = bf_trunc(t - bf_to_f(hi));                        \
        *(short*)((char*)hpl_hi[HB] + woh[r]) = (short)hi;                    \
        *(short*)((char*)hpl_lo[HB] + woh[r]) = (short)lo;                    \
    }                                                                         \
    /* convert x_{S+1} (loaded one step ago) -> xpl[HB] */                    \
    {                                                                         \
        unsigned short h0 = bf_trunc(XGC.x), h1 = bf_trunc(XGC.y);            \
        unsigned short g0 = bf_trunc(XGC.x - bf_to_f(h0));                    \
        unsigned short g1 = bf_trunc(XGC.y - bf_to_f(h1));                    \
        *(unsigned*)((char*)xpl_hi[HB] + wox) = (unsigned)h0|((unsigned)h1<<16);\
        *(unsigned*)((char*)xpl_lo[HB] + wox) = (unsigned)g0|((unsigned)g1<<16);\
    }                                                                         \
    LDS_BARRIER();                                                            \
    /* A-fragments for step S+1 */                                            \
    _Pragma("unroll")                                                         \
    for (int c = 0; c < 4; ++c) {                                             \
        ah[c] = *(const bf16x8*)((const char*)hpl_hi[HB] + hro[c]);           \
        al[c] = *(const bf16x8*)((const char*)hpl_lo[HB] + hro[c]);           \
    }                                                                         \
    _Pragma("unroll")                                                         \
    for (int c = 0; c < 2; ++c) {                                             \
        xh[c] = *(const bf16x8*)((const char*)xpl_hi[HB] + xro[c]);           \
        xl[c] = *(const bf16x8*)((const char*)xpl_lo[HB] + xro[c]);           \
    }                                                                         \
}

    for (int s2 = 0; s2 < S_LEN; s2 += 2) {
        STEP(s2,     xgA, xgB, 1);   // even: convert xgA (x_{s+1}), load xgB
        STEP(s2 + 1, xgB, xgA, 0);   // odd:  convert xgB,            load xgA
    }
#undef STEP

    // ---- h_last = h_S, reconstructed from hpl[0] (last HB was 0) ----
    #pragma unroll
    for (int r = 0; r < 4; ++r) {
        int row = (l4 << 2) + r;
        unsigned short hi = (unsigned short)*(short*)((char*)hpl_hi[0] + woh[r]);
        unsigned short lo = (unsigned short)*(short*)((char*)hpl_lo[0] + woh[r]);
        float hv = bf_to_f(hi) + bf_to_f(lo);
        out[(size_t)S_LEN * B_SZ * H_SZ + (size_t)(b0 + row) * H_SZ + unit] = hv;
    }
}

extern "C" void kernel_launch(void* const* d_in, const int* in_sizes, int n_in,
                              void* d_out, int out_size, void* d_ws, size_t ws_size,
                              hipStream_t stream) {
    const float* x  = (const float*)d_in[0];
    const float* W1 = (const float*)d_in[1];
    const float* b1 = (const float*)d_in[2];
    const float* W2 = (const float*)d_in[3];
    const float* b2 = (const float*)d_in[4];
    float* out = (float*)d_out;

    rnn_mfma<<<dim3(B_SZ / BT), dim3(BLK), 0, stream>>>(x, W1, b1, W2, b2, out);
}